// Round 1
// baseline (197.788 us; speedup 1.0000x reference)
//
#include <hip/hip_runtime.h>
#include <math.h>

#define NQ      512
#define DMODEL  256
#define DINNER  512
#define NH      8
#define DHEAD   64
#define SCALE   0.125f
#define PI_F    3.14159265358979323846f

// workspace layout (float offsets)
#define Q_OFF   0           // 512*512
#define KC_OFF  262144      // 512*512
#define V_OFF   524288      // 512*512
#define QW_OFF  786432      // 512*528
#define SC_OFF  1114112     // 8*512*512
#define IN_OFF  3211264     // 512*512
// total 3473408 floats = 13.9 MB

// ---------------------------------------------------------------- K1: q/kc/v
__global__ __launch_bounds__(256) void k_proj(
    const float* __restrict__ x, const float* __restrict__ Wq,
    const float* __restrict__ Wk, const float* __restrict__ Wv,
    float* __restrict__ ws)
{
    const int z = blockIdx.z;
    const float* W = (z == 0) ? Wq : (z == 1) ? Wk : Wv;
    float* out = ws + ((z == 0) ? Q_OFF : (z == 1) ? KC_OFF : V_OFF);

    __shared__ alignas(16) float Xs[32][68];
    __shared__ alignas(16) float Bs[32][64];

    const int tx = threadIdx.x, ty = threadIdx.y;
    const int tid = ty * 16 + tx;
    const int row0 = blockIdx.y * 64, col0 = blockIdx.x * 64;

    float acc[4][4] = {};

    for (int k0 = 0; k0 < DMODEL; k0 += 32) {
        {
            const int m = tid >> 2;
            const int kk0 = (tid & 3) * 8;
            const float* src = x + (row0 + m) * DMODEL + k0 + kk0;
            float4 a0 = *(const float4*)(src);
            float4 a1 = *(const float4*)(src + 4);
            Xs[kk0 + 0][m] = a0.x; Xs[kk0 + 1][m] = a0.y;
            Xs[kk0 + 2][m] = a0.z; Xs[kk0 + 3][m] = a0.w;
            Xs[kk0 + 4][m] = a1.x; Xs[kk0 + 5][m] = a1.y;
            Xs[kk0 + 6][m] = a1.z; Xs[kk0 + 7][m] = a1.w;
        }
        {
            const int kk = tid >> 3;
            const int n0 = (tid & 7) * 8;
            const float* src = W + (k0 + kk) * DINNER + col0 + n0;
            *(float4*)&Bs[kk][n0]     = *(const float4*)(src);
            *(float4*)&Bs[kk][n0 + 4] = *(const float4*)(src + 4);
        }
        __syncthreads();
        #pragma unroll
        for (int kk = 0; kk < 32; ++kk) {
            float4 a4 = *(const float4*)&Xs[kk][ty * 4];
            float4 b4 = *(const float4*)&Bs[kk][tx * 4];
            float a[4] = {a4.x, a4.y, a4.z, a4.w};
            float b[4] = {b4.x, b4.y, b4.z, b4.w};
            #pragma unroll
            for (int ia = 0; ia < 4; ++ia)
                #pragma unroll
                for (int ib = 0; ib < 4; ++ib)
                    acc[ia][ib] += a[ia] * b[ib];
        }
        __syncthreads();
    }
    #pragma unroll
    for (int ia = 0; ia < 4; ++ia) {
        float4 o = make_float4(acc[ia][0], acc[ia][1], acc[ia][2], acc[ia][3]);
        *(float4*)&out[(row0 + ty * 4 + ia) * DINNER + col0 + tx * 4] = o;
    }
}

// ------------------------------------------------- K1b: qW[i][slot], scaled
// slot layout: bands b=0..15: [b*32 + f*8 + h], f:0=sin_x 1=cos_x 2=sin_y 3=cos_y
// then dx -> 512+h, dy -> 520+h   (528 per row i)
__global__ __launch_bounds__(256) void k_qw(
    const float* __restrict__ Wk, float* __restrict__ ws)
{
    const float* q = ws + Q_OFF;
    float* qW = ws + QW_OFF;
    const int h = blockIdx.x >> 3;
    const int i0 = (blockIdx.x & 7) * 64;

    __shared__ float Wr[66][64];
    __shared__ float Qs[64][65];
    const int tid = threadIdx.x;

    for (int idx = tid; idx < 66 * 64; idx += 256) {
        int r = idx >> 6, d = idx & 63;
        Wr[r][d] = Wk[(DMODEL + r) * DINNER + h * DHEAD + d];
    }
    for (int idx = tid; idx < 64 * 64; idx += 256) {
        int m = idx >> 6, d = idx & 63;
        Qs[m][d] = q[(i0 + m) * DINNER + h * DHEAD + d];
    }
    __syncthreads();
    for (int idx = tid; idx < 64 * 66; idx += 256) {
        int m = idx / 66, r = idx - m * 66;
        float acc = 0.f;
        #pragma unroll 8
        for (int d = 0; d < 64; ++d) acc += Qs[m][d] * Wr[r][d];
        int slot;
        if      (r < 16)  slot = r * 32 + 0 + h;          // sin_x band r
        else if (r < 32)  slot = (r - 16) * 32 + 8 + h;   // cos_x
        else if (r == 32) slot = 512 + h;                 // dx
        else if (r < 49)  slot = (r - 33) * 32 + 16 + h;  // sin_y
        else if (r < 65)  slot = (r - 49) * 32 + 24 + h;  // cos_y
        else              slot = 520 + h;                 // dy
        qW[(i0 + m) * 528 + slot] = acc * SCALE;
    }
}

// -------------------------------------- K2a: content scores (batched GEMM)
__global__ __launch_bounds__(256) void k_content(float* __restrict__ ws)
{
    const float* q  = ws + Q_OFF;
    const float* kc = ws + KC_OFF;
    float* sc = ws + SC_OFF;
    const int h = blockIdx.z;
    const int i0 = blockIdx.y * 64, j0 = blockIdx.x * 64;

    __shared__ alignas(16) float Qs[64][68];   // [d][m]
    __shared__ alignas(16) float Ks[64][68];   // [d][n]
    const int tx = threadIdx.x, ty = threadIdx.y;
    const int tid = ty * 16 + tx;
    {
        const int m = tid >> 2;
        const int d0 = (tid & 3) * 16;
        const float* qs = q  + (i0 + m) * DINNER + h * DHEAD + d0;
        const float* ks = kc + (j0 + m) * DINNER + h * DHEAD + d0;
        #pragma unroll
        for (int l = 0; l < 16; ++l) {
            Qs[d0 + l][m] = qs[l];
            Ks[d0 + l][m] = ks[l];
        }
    }
    __syncthreads();
    float acc[4][4] = {};
    #pragma unroll 8
    for (int d = 0; d < 64; ++d) {
        float4 a4 = *(const float4*)&Qs[d][ty * 4];
        float4 b4 = *(const float4*)&Ks[d][tx * 4];
        float a[4] = {a4.x, a4.y, a4.z, a4.w};
        float b[4] = {b4.x, b4.y, b4.z, b4.w};
        #pragma unroll
        for (int ia = 0; ia < 4; ++ia)
            #pragma unroll
            for (int ib = 0; ib < 4; ++ib)
                acc[ia][ib] += a[ia] * b[ib];
    }
    #pragma unroll
    for (int ia = 0; ia < 4; ++ia) {
        float4 o = make_float4(acc[ia][0] * SCALE, acc[ia][1] * SCALE,
                               acc[ia][2] * SCALE, acc[ia][3] * SCALE);
        *(float4*)&sc[((h * NQ) + i0 + ty * 4 + ia) * NQ + j0 + tx * 4] = o;
    }
}

// --------------------- K2b: rpe scores + softmax (per query row i, in-place)
__global__ __launch_bounds__(256) void k_rpe_softmax(
    const float* __restrict__ pos, float* __restrict__ ws)
{
    const float* qW = ws + QW_OFF;
    float* sc = ws + SC_OFF;
    const int i = blockIdx.x;
    const int tid = threadIdx.x;

    __shared__ alignas(16) float qw[528];
    __shared__ float pbuf[8][512];
    __shared__ float red[8];

    for (int idx = tid; idx < 528; idx += 256) qw[idx] = qW[i * 528 + idx];
    __syncthreads();

    const float pxi = pos[i * 2 + 0];
    const float pyi = pos[i * 2 + 1];
    const float4* qw4 = (const float4*)qw;

    #pragma unroll
    for (int jj = 0; jj < 2; ++jj) {
        const int j = tid + jj * 256;
        float dxr = (pos[j * 2 + 0] - pxi) * (1.0f / 51.0f);
        float dyr = (pos[j * 2 + 1] - pyi) * (1.0f / 51.0f);
        float dx = dxr / (1.0f + fabsf(dxr));
        float dy = dyr / (1.0f + fabsf(dyr));

        float s[8];
        #pragma unroll
        for (int h = 0; h < 8; ++h) s[h] = sc[((h * NQ) + i) * NQ + j];

        // sin/cos ladder: angle_b = dx*pi*(1 + b*7/15) -> rotation recurrence
        float sx, cx, sy, cy, sxp, cxp, syp, cyp;
        __sincosf(dx * PI_F, &sx, &cx);
        __sincosf(dx * (PI_F * 7.0f / 15.0f), &sxp, &cxp);
        __sincosf(dy * PI_F, &sy, &cy);
        __sincosf(dy * (PI_F * 7.0f / 15.0f), &syp, &cyp);

        #pragma unroll
        for (int b = 0; b < 16; ++b) {
            float4 wsx0 = qw4[b * 8 + 0], wsx1 = qw4[b * 8 + 1];
            float4 wcx0 = qw4[b * 8 + 2], wcx1 = qw4[b * 8 + 3];
            float4 wsy0 = qw4[b * 8 + 4], wsy1 = qw4[b * 8 + 5];
            float4 wcy0 = qw4[b * 8 + 6], wcy1 = qw4[b * 8 + 7];
            s[0] += sx * wsx0.x + cx * wcx0.x + sy * wsy0.x + cy * wcy0.x;
            s[1] += sx * wsx0.y + cx * wcx0.y + sy * wsy0.y + cy * wcy0.y;
            s[2] += sx * wsx0.z + cx * wcx0.z + sy * wsy0.z + cy * wcy0.z;
            s[3] += sx * wsx0.w + cx * wcx0.w + sy * wsy0.w + cy * wcy0.w;
            s[4] += sx * wsx1.x + cx * wcx1.x + sy * wsy1.x + cy * wcy1.x;
            s[5] += sx * wsx1.y + cx * wcx1.y + sy * wsy1.y + cy * wcy1.y;
            s[6] += sx * wsx1.z + cx * wcx1.z + sy * wsy1.z + cy * wcy1.z;
            s[7] += sx * wsx1.w + cx * wcx1.w + sy * wsy1.w + cy * wcy1.w;
            float t;
            t = sx * cxp + cx * sxp; cx = cx * cxp - sx * sxp; sx = t;
            t = sy * cyp + cy * syp; cy = cy * cyp - sy * syp; sy = t;
        }
        {
            float4 wdx0 = qw4[128], wdx1 = qw4[129];
            float4 wdy0 = qw4[130], wdy1 = qw4[131];
            s[0] += dx * wdx0.x + dy * wdy0.x;
            s[1] += dx * wdx0.y + dy * wdy0.y;
            s[2] += dx * wdx0.z + dy * wdy0.z;
            s[3] += dx * wdx0.w + dy * wdy0.w;
            s[4] += dx * wdx1.x + dy * wdy1.x;
            s[5] += dx * wdx1.y + dy * wdy1.y;
            s[6] += dx * wdx1.z + dy * wdy1.z;
            s[7] += dx * wdx1.w + dy * wdy1.w;
        }
        #pragma unroll
        for (int h = 0; h < 8; ++h) pbuf[h][j] = s[h];
    }
    __syncthreads();

    const int wave = tid >> 6, lane = tid & 63;
    for (int h = wave * 2; h < wave * 2 + 2; ++h) {
        float m = -1e30f;
        for (int jj2 = lane; jj2 < 512; jj2 += 64) m = fmaxf(m, pbuf[h][jj2]);
        #pragma unroll
        for (int off = 32; off; off >>= 1) m = fmaxf(m, __shfl_xor(m, off));
        float sum = 0.f;
        for (int jj2 = lane; jj2 < 512; jj2 += 64) {
            float e = __expf(pbuf[h][jj2] - m);
            pbuf[h][jj2] = e;
            sum += e;
        }
        #pragma unroll
        for (int off = 32; off; off >>= 1) sum += __shfl_xor(sum, off);
        if (lane == 0) red[h] = 1.0f / sum;
    }
    __syncthreads();
    #pragma unroll
    for (int h = 0; h < 8; ++h) {
        const float inv = red[h];
        sc[((h * NQ) + i) * NQ + tid]       = pbuf[h][tid] * inv;
        sc[((h * NQ) + i) * NQ + tid + 256] = pbuf[h][tid + 256] * inv;
    }
}

// ------------------------------------------------ K4: inner = attn @ v
__global__ __launch_bounds__(256) void k_av(float* __restrict__ ws)
{
    const float* attn = ws + SC_OFF;
    const float* v    = ws + V_OFF;
    float* inner      = ws + IN_OFF;
    const int h  = blockIdx.y;
    const int i0 = blockIdx.x * 32;

    __shared__ alignas(16) float As[32][36];   // [kk][m]
    __shared__ alignas(16) float Vs[32][64];   // [kk][d]
    const int tx = threadIdx.x, ty = threadIdx.y;
    const int tid = ty * 16 + tx;

    float acc[2][4] = {};
    for (int k0 = 0; k0 < NQ; k0 += 32) {
        {
            const int m = tid >> 3;
            const int kk0 = (tid & 7) * 4;
            float4 a4 = *(const float4*)&attn[((h * NQ) + i0 + m) * NQ + k0 + kk0];
            As[kk0 + 0][m] = a4.x; As[kk0 + 1][m] = a4.y;
            As[kk0 + 2][m] = a4.z; As[kk0 + 3][m] = a4.w;
        }
        {
            const int kk = tid >> 3;
            const int n0 = (tid & 7) * 8;
            const float* src = v + (k0 + kk) * DINNER + h * DHEAD + n0;
            *(float4*)&Vs[kk][n0]     = *(const float4*)(src);
            *(float4*)&Vs[kk][n0 + 4] = *(const float4*)(src + 4);
        }
        __syncthreads();
        #pragma unroll
        for (int kk = 0; kk < 32; ++kk) {
            float2 a2 = *(const float2*)&As[kk][ty * 2];
            float4 b4 = *(const float4*)&Vs[kk][tx * 4];
            float b[4] = {b4.x, b4.y, b4.z, b4.w};
            #pragma unroll
            for (int ib = 0; ib < 4; ++ib) {
                acc[0][ib] += a2.x * b[ib];
                acc[1][ib] += a2.y * b[ib];
            }
        }
        __syncthreads();
    }
    #pragma unroll
    for (int ia = 0; ia < 2; ++ia) {
        float4 o = make_float4(acc[ia][0], acc[ia][1], acc[ia][2], acc[ia][3]);
        *(float4*)&inner[(i0 + ty * 2 + ia) * DINNER + h * DHEAD + tx * 4] = o;
    }
}

// ------------------------------------------------ K5: out = inner @ Wo + bo
__global__ __launch_bounds__(256) void k_out(
    const float* __restrict__ Wo, const float* __restrict__ bo,
    float* __restrict__ ws, float* __restrict__ outp)
{
    const float* inner = ws + IN_OFF;
    const int c0 = blockIdx.x * 32;
    const int i0 = blockIdx.y * 32;

    __shared__ alignas(16) float Xs[32][36];   // [kk][m]
    __shared__ alignas(16) float Bs[32][32];   // [kk][n]
    const int tx = threadIdx.x, ty = threadIdx.y;
    const int tid = ty * 16 + tx;

    float acc[2][2] = {};
    for (int k0 = 0; k0 < DINNER; k0 += 32) {
        {
            const int m = tid >> 3;
            const int kk0 = (tid & 7) * 4;
            float4 a4 = *(const float4*)&inner[(i0 + m) * DINNER + k0 + kk0];
            Xs[kk0 + 0][m] = a4.x; Xs[kk0 + 1][m] = a4.y;
            Xs[kk0 + 2][m] = a4.z; Xs[kk0 + 3][m] = a4.w;
        }
        {
            const int kk = tid >> 3;
            const int n0 = (tid & 7) * 4;
            *(float4*)&Bs[kk][n0] = *(const float4*)&Wo[(k0 + kk) * DMODEL + c0 + n0];
        }
        __syncthreads();
        #pragma unroll
        for (int kk = 0; kk < 32; ++kk) {
            float2 a2 = *(const float2*)&Xs[kk][ty * 2];
            float2 b2 = *(const float2*)&Bs[kk][tx * 2];
            acc[0][0] += a2.x * b2.x;
            acc[0][1] += a2.x * b2.y;
            acc[1][0] += a2.y * b2.x;
            acc[1][1] += a2.y * b2.y;
        }
        __syncthreads();
    }
    #pragma unroll
    for (int ia = 0; ia < 2; ++ia) {
        float2 o;
        o.x = acc[ia][0] + bo[c0 + tx * 2 + 0];
        o.y = acc[ia][1] + bo[c0 + tx * 2 + 1];
        *(float2*)&outp[(i0 + ty * 2 + ia) * DMODEL + c0 + tx * 2] = o;
    }
}

extern "C" void kernel_launch(void* const* d_in, const int* in_sizes, int n_in,
                              void* d_out, int out_size, void* d_ws, size_t ws_size,
                              hipStream_t stream)
{
    const float* x   = (const float*)d_in[0];
    const float* pos = (const float*)d_in[1];
    const float* Wq  = (const float*)d_in[2];
    const float* Wk  = (const float*)d_in[3];
    const float* Wv  = (const float*)d_in[4];
    const float* Wo  = (const float*)d_in[5];
    const float* bo  = (const float*)d_in[6];
    float* out = (float*)d_out;
    float* ws  = (float*)d_ws;

    k_proj<<<dim3(8, 8, 3), dim3(16, 16), 0, stream>>>(x, Wq, Wk, Wv, ws);
    k_qw<<<dim3(64), dim3(256), 0, stream>>>(Wk, ws);
    k_content<<<dim3(8, 8, 8), dim3(16, 16), 0, stream>>>(ws);
    k_rpe_softmax<<<dim3(512), dim3(256), 0, stream>>>(pos, ws);
    k_av<<<dim3(16, 8), dim3(16, 16), 0, stream>>>(ws);
    k_out<<<dim3(8, 16), dim3(16, 16), 0, stream>>>(Wo, bo, ws, out);
}

// Round 2
// 166.945 us; speedup vs baseline: 1.1847x; 1.1847x over previous
//
#include <hip/hip_runtime.h>
#include <math.h>

#define NQ      512
#define DMODEL  256
#define DINNER  512
#define NH      8
#define DHEAD   64
#define SCALE   0.125f
#define PI_F    3.14159265358979323846f

// workspace layout (float offsets)
#define Q_OFF   0           // 512*512
#define KC_OFF  262144      // 512*512
#define V_OFF   524288      // 512*512
#define QW_OFF  786432      // 512*528
#define SC_OFF  1114112     // 8*512*512
#define IN_OFF  3211264     // 512*512
// total 3473408 floats = 13.9 MB

// ---------------------------------------------------------------- K1: q/kc/v
__global__ __launch_bounds__(256) void k_proj(
    const float* __restrict__ x, const float* __restrict__ Wq,
    const float* __restrict__ Wk, const float* __restrict__ Wv,
    float* __restrict__ ws)
{
    const int z = blockIdx.z;
    const float* W = (z == 0) ? Wq : (z == 1) ? Wk : Wv;
    float* out = ws + ((z == 0) ? Q_OFF : (z == 1) ? KC_OFF : V_OFF);

    __shared__ alignas(16) float Xs[32][68];
    __shared__ alignas(16) float Bs[32][64];

    const int tx = threadIdx.x, ty = threadIdx.y;
    const int tid = ty * 16 + tx;
    const int row0 = blockIdx.y * 64, col0 = blockIdx.x * 64;

    float acc[4][4] = {};

    for (int k0 = 0; k0 < DMODEL; k0 += 32) {
        {
            const int m = tid >> 2;
            const int kk0 = (tid & 3) * 8;
            const float* src = x + (row0 + m) * DMODEL + k0 + kk0;
            float4 a0 = *(const float4*)(src);
            float4 a1 = *(const float4*)(src + 4);
            Xs[kk0 + 0][m] = a0.x; Xs[kk0 + 1][m] = a0.y;
            Xs[kk0 + 2][m] = a0.z; Xs[kk0 + 3][m] = a0.w;
            Xs[kk0 + 4][m] = a1.x; Xs[kk0 + 5][m] = a1.y;
            Xs[kk0 + 6][m] = a1.z; Xs[kk0 + 7][m] = a1.w;
        }
        {
            const int kk = tid >> 3;
            const int n0 = (tid & 7) * 8;
            const float* src = W + (k0 + kk) * DINNER + col0 + n0;
            *(float4*)&Bs[kk][n0]     = *(const float4*)(src);
            *(float4*)&Bs[kk][n0 + 4] = *(const float4*)(src + 4);
        }
        __syncthreads();
        #pragma unroll
        for (int kk = 0; kk < 32; ++kk) {
            float4 a4 = *(const float4*)&Xs[kk][ty * 4];
            float4 b4 = *(const float4*)&Bs[kk][tx * 4];
            float a[4] = {a4.x, a4.y, a4.z, a4.w};
            float b[4] = {b4.x, b4.y, b4.z, b4.w};
            #pragma unroll
            for (int ia = 0; ia < 4; ++ia)
                #pragma unroll
                for (int ib = 0; ib < 4; ++ib)
                    acc[ia][ib] += a[ia] * b[ib];
        }
        __syncthreads();
    }
    #pragma unroll
    for (int ia = 0; ia < 4; ++ia) {
        float4 o = make_float4(acc[ia][0], acc[ia][1], acc[ia][2], acc[ia][3]);
        *(float4*)&out[(row0 + ty * 4 + ia) * DINNER + col0 + tx * 4] = o;
    }
}

// ------------------------------------------------- K1b: qW[i][slot], scaled
// slot layout: bands b=0..15: [b*32 + f*8 + h], f:0=sin_x 1=cos_x 2=sin_y 3=cos_y
// then dx -> 512+h, dy -> 520+h   (528 per row i)
// v2: WrT transposed in LDS (conflict-free), Qs broadcast float4, 128 blocks.
__global__ __launch_bounds__(256) void k_qw(
    const float* __restrict__ Wk, float* __restrict__ ws)
{
    const float* q = ws + Q_OFF;
    float* qW = ws + QW_OFF;
    const int h  = blockIdx.x >> 4;          // 8 heads
    const int i0 = (blockIdx.x & 15) * 32;   // 16 row-tiles of 32

    __shared__ float WrT[64][67];            // [d][r], pad 67 (write stride 67%32=3 -> free)
    __shared__ alignas(16) float Qs[32][68]; // [m][d], rows 16B-aligned
    const int tid = threadIdx.x;

    // WrT load: d fastest -> coalesced global; LDS write stride 67 floats -> 2-way max
    for (int idx = tid; idx < 66 * 64; idx += 256) {
        int r = idx >> 6, d = idx & 63;
        WrT[d][r] = Wk[(DMODEL + r) * DINNER + h * DHEAD + d];
    }
    for (int idx = tid; idx < 32 * 16; idx += 256) {
        int m = idx >> 4, dq = (idx & 15) * 4;
        *(float4*)&Qs[m][dq] = *(const float4*)&q[(i0 + m) * DINNER + h * DHEAD + dq];
    }
    __syncthreads();

    for (int idx = tid; idx < 32 * 66; idx += 256) {
        int m = idx / 66, r = idx - m * 66;
        float acc = 0.f;
        #pragma unroll
        for (int d0 = 0; d0 < 64; d0 += 4) {
            float4 qf = *(const float4*)&Qs[m][d0];      // broadcast (same m per group)
            acc += qf.x * WrT[d0 + 0][r] + qf.y * WrT[d0 + 1][r]
                 + qf.z * WrT[d0 + 2][r] + qf.w * WrT[d0 + 3][r];  // consecutive r -> free
        }
        int slot;
        if      (r < 16)  slot = r * 32 + 0 + h;          // sin_x band r
        else if (r < 32)  slot = (r - 16) * 32 + 8 + h;   // cos_x
        else if (r == 32) slot = 512 + h;                 // dx
        else if (r < 49)  slot = (r - 33) * 32 + 16 + h;  // sin_y
        else if (r < 65)  slot = (r - 49) * 32 + 24 + h;  // cos_y
        else              slot = 520 + h;                 // dy
        qW[(i0 + m) * 528 + slot] = acc * SCALE;
    }
}

// -------------------------------------- K2a: content scores (batched GEMM)
__global__ __launch_bounds__(256) void k_content(float* __restrict__ ws)
{
    const float* q  = ws + Q_OFF;
    const float* kc = ws + KC_OFF;
    float* sc = ws + SC_OFF;
    const int h = blockIdx.z;
    const int i0 = blockIdx.y * 64, j0 = blockIdx.x * 64;

    __shared__ alignas(16) float Qs[64][68];   // [d][m]
    __shared__ alignas(16) float Ks[64][68];   // [d][n]
    const int tx = threadIdx.x, ty = threadIdx.y;
    const int tid = ty * 16 + tx;
    {
        const int m = tid >> 2;
        const int d0 = (tid & 3) * 16;
        const float* qs = q  + (i0 + m) * DINNER + h * DHEAD + d0;
        const float* ks = kc + (j0 + m) * DINNER + h * DHEAD + d0;
        #pragma unroll
        for (int l = 0; l < 16; ++l) {
            Qs[d0 + l][m] = qs[l];
            Ks[d0 + l][m] = ks[l];
        }
    }
    __syncthreads();
    float acc[4][4] = {};
    #pragma unroll 8
    for (int d = 0; d < 64; ++d) {
        float4 a4 = *(const float4*)&Qs[d][ty * 4];
        float4 b4 = *(const float4*)&Ks[d][tx * 4];
        float a[4] = {a4.x, a4.y, a4.z, a4.w};
        float b[4] = {b4.x, b4.y, b4.z, b4.w};
        #pragma unroll
        for (int ia = 0; ia < 4; ++ia)
            #pragma unroll
            for (int ib = 0; ib < 4; ++ib)
                acc[ia][ib] += a[ia] * b[ib];
    }
    #pragma unroll
    for (int ia = 0; ia < 4; ++ia) {
        float4 o = make_float4(acc[ia][0] * SCALE, acc[ia][1] * SCALE,
                               acc[ia][2] * SCALE, acc[ia][3] * SCALE);
        *(float4*)&sc[((h * NQ) + i0 + ty * 4 + ia) * NQ + j0 + tx * 4] = o;
    }
}

// --------------------- K2b: rpe scores + softmax (per query row i, in-place)
__global__ __launch_bounds__(256) void k_rpe_softmax(
    const float* __restrict__ pos, float* __restrict__ ws)
{
    const float* qW = ws + QW_OFF;
    float* sc = ws + SC_OFF;
    const int i = blockIdx.x;
    const int tid = threadIdx.x;

    __shared__ alignas(16) float qw[528];
    __shared__ float pbuf[8][512];
    __shared__ float red[8];

    for (int idx = tid; idx < 528; idx += 256) qw[idx] = qW[i * 528 + idx];
    __syncthreads();

    const float pxi = pos[i * 2 + 0];
    const float pyi = pos[i * 2 + 1];
    const float4* qw4 = (const float4*)qw;

    #pragma unroll
    for (int jj = 0; jj < 2; ++jj) {
        const int j = tid + jj * 256;
        float dxr = (pos[j * 2 + 0] - pxi) * (1.0f / 51.0f);
        float dyr = (pos[j * 2 + 1] - pyi) * (1.0f / 51.0f);
        float dx = dxr / (1.0f + fabsf(dxr));
        float dy = dyr / (1.0f + fabsf(dyr));

        float s[8];
        #pragma unroll
        for (int h = 0; h < 8; ++h) s[h] = sc[((h * NQ) + i) * NQ + j];

        // sin/cos ladder: angle_b = dx*pi*(1 + b*7/15) -> rotation recurrence
        float sx, cx, sy, cy, sxp, cxp, syp, cyp;
        __sincosf(dx * PI_F, &sx, &cx);
        __sincosf(dx * (PI_F * 7.0f / 15.0f), &sxp, &cxp);
        __sincosf(dy * PI_F, &sy, &cy);
        __sincosf(dy * (PI_F * 7.0f / 15.0f), &syp, &cyp);

        #pragma unroll
        for (int b = 0; b < 16; ++b) {
            float4 wsx0 = qw4[b * 8 + 0], wsx1 = qw4[b * 8 + 1];
            float4 wcx0 = qw4[b * 8 + 2], wcx1 = qw4[b * 8 + 3];
            float4 wsy0 = qw4[b * 8 + 4], wsy1 = qw4[b * 8 + 5];
            float4 wcy0 = qw4[b * 8 + 6], wcy1 = qw4[b * 8 + 7];
            s[0] += sx * wsx0.x + cx * wcx0.x + sy * wsy0.x + cy * wcy0.x;
            s[1] += sx * wsx0.y + cx * wcx0.y + sy * wsy0.y + cy * wcy0.y;
            s[2] += sx * wsx0.z + cx * wcx0.z + sy * wsy0.z + cy * wcy0.z;
            s[3] += sx * wsx0.w + cx * wcx0.w + sy * wsy0.w + cy * wcy0.w;
            s[4] += sx * wsx1.x + cx * wcx1.x + sy * wsy1.x + cy * wcy1.x;
            s[5] += sx * wsx1.y + cx * wcx1.y + sy * wsy1.y + cy * wcy1.y;
            s[6] += sx * wsx1.z + cx * wcx1.z + sy * wsy1.z + cy * wcy1.z;
            s[7] += sx * wsx1.w + cx * wcx1.w + sy * wsy1.w + cy * wcy1.w;
            float t;
            t = sx * cxp + cx * sxp; cx = cx * cxp - sx * sxp; sx = t;
            t = sy * cyp + cy * syp; cy = cy * cyp - sy * syp; sy = t;
        }
        {
            float4 wdx0 = qw4[128], wdx1 = qw4[129];
            float4 wdy0 = qw4[130], wdy1 = qw4[131];
            s[0] += dx * wdx0.x + dy * wdy0.x;
            s[1] += dx * wdx0.y + dy * wdy0.y;
            s[2] += dx * wdx0.z + dy * wdy0.z;
            s[3] += dx * wdx0.w + dy * wdy0.w;
            s[4] += dx * wdx1.x + dy * wdy1.x;
            s[5] += dx * wdx1.y + dy * wdy1.y;
            s[6] += dx * wdx1.z + dy * wdy1.z;
            s[7] += dx * wdx1.w + dy * wdy1.w;
        }
        #pragma unroll
        for (int h = 0; h < 8; ++h) pbuf[h][j] = s[h];
    }
    __syncthreads();

    const int wave = tid >> 6, lane = tid & 63;
    for (int h = wave * 2; h < wave * 2 + 2; ++h) {
        float m = -1e30f;
        for (int jj2 = lane; jj2 < 512; jj2 += 64) m = fmaxf(m, pbuf[h][jj2]);
        #pragma unroll
        for (int off = 32; off; off >>= 1) m = fmaxf(m, __shfl_xor(m, off));
        float sum = 0.f;
        for (int jj2 = lane; jj2 < 512; jj2 += 64) {
            float e = __expf(pbuf[h][jj2] - m);
            pbuf[h][jj2] = e;
            sum += e;
        }
        #pragma unroll
        for (int off = 32; off; off >>= 1) sum += __shfl_xor(sum, off);
        if (lane == 0) red[h] = 1.0f / sum;
    }
    __syncthreads();
    #pragma unroll
    for (int h = 0; h < 8; ++h) {
        const float inv = red[h];
        sc[((h * NQ) + i) * NQ + tid]       = pbuf[h][tid] * inv;
        sc[((h * NQ) + i) * NQ + tid + 256] = pbuf[h][tid + 256] * inv;
    }
}

// ------------------------------------------------ K4: inner = attn @ v
__global__ __launch_bounds__(256) void k_av(float* __restrict__ ws)
{
    const float* attn = ws + SC_OFF;
    const float* v    = ws + V_OFF;
    float* inner      = ws + IN_OFF;
    const int h  = blockIdx.y;
    const int i0 = blockIdx.x * 32;

    __shared__ alignas(16) float As[32][36];   // [kk][m]
    __shared__ alignas(16) float Vs[32][64];   // [kk][d]
    const int tx = threadIdx.x, ty = threadIdx.y;
    const int tid = ty * 16 + tx;

    float acc[2][4] = {};
    for (int k0 = 0; k0 < NQ; k0 += 32) {
        {
            const int m = tid >> 3;
            const int kk0 = (tid & 7) * 4;
            float4 a4 = *(const float4*)&attn[((h * NQ) + i0 + m) * NQ + k0 + kk0];
            As[kk0 + 0][m] = a4.x; As[kk0 + 1][m] = a4.y;
            As[kk0 + 2][m] = a4.z; As[kk0 + 3][m] = a4.w;
        }
        {
            const int kk = tid >> 3;
            const int n0 = (tid & 7) * 8;
            const float* src = v + (k0 + kk) * DINNER + h * DHEAD + n0;
            *(float4*)&Vs[kk][n0]     = *(const float4*)(src);
            *(float4*)&Vs[kk][n0 + 4] = *(const float4*)(src + 4);
        }
        __syncthreads();
        #pragma unroll
        for (int kk = 0; kk < 32; ++kk) {
            float2 a2 = *(const float2*)&As[kk][ty * 2];
            float4 b4 = *(const float4*)&Vs[kk][tx * 4];
            float b[4] = {b4.x, b4.y, b4.z, b4.w};
            #pragma unroll
            for (int ib = 0; ib < 4; ++ib) {
                acc[0][ib] += a2.x * b[ib];
                acc[1][ib] += a2.y * b[ib];
            }
        }
        __syncthreads();
    }
    #pragma unroll
    for (int ia = 0; ia < 2; ++ia) {
        float4 o = make_float4(acc[ia][0], acc[ia][1], acc[ia][2], acc[ia][3]);
        *(float4*)&inner[(i0 + ty * 2 + ia) * DINNER + h * DHEAD + tx * 4] = o;
    }
}

// ------------------------------------------------ K5: out = inner @ Wo + bo
__global__ __launch_bounds__(256) void k_out(
    const float* __restrict__ Wo, const float* __restrict__ bo,
    float* __restrict__ ws, float* __restrict__ outp)
{
    const float* inner = ws + IN_OFF;
    const int c0 = blockIdx.x * 32;
    const int i0 = blockIdx.y * 32;

    __shared__ alignas(16) float Xs[32][36];   // [kk][m]
    __shared__ alignas(16) float Bs[32][32];   // [kk][n]
    const int tx = threadIdx.x, ty = threadIdx.y;
    const int tid = ty * 16 + tx;

    float acc[2][2] = {};
    for (int k0 = 0; k0 < DINNER; k0 += 32) {
        {
            const int m = tid >> 3;
            const int kk0 = (tid & 7) * 4;
            float4 a4 = *(const float4*)&inner[(i0 + m) * DINNER + k0 + kk0];
            Xs[kk0 + 0][m] = a4.x; Xs[kk0 + 1][m] = a4.y;
            Xs[kk0 + 2][m] = a4.z; Xs[kk0 + 3][m] = a4.w;
        }
        {
            const int kk = tid >> 3;
            const int n0 = (tid & 7) * 4;
            *(float4*)&Bs[kk][n0] = *(const float4*)&Wo[(k0 + kk) * DMODEL + c0 + n0];
        }
        __syncthreads();
        #pragma unroll
        for (int kk = 0; kk < 32; ++kk) {
            float2 a2 = *(const float2*)&Xs[kk][ty * 2];
            float2 b2 = *(const float2*)&Bs[kk][tx * 2];
            acc[0][0] += a2.x * b2.x;
            acc[0][1] += a2.x * b2.y;
            acc[1][0] += a2.y * b2.x;
            acc[1][1] += a2.y * b2.y;
        }
        __syncthreads();
    }
    #pragma unroll
    for (int ia = 0; ia < 2; ++ia) {
        float2 o;
        o.x = acc[ia][0] + bo[c0 + tx * 2 + 0];
        o.y = acc[ia][1] + bo[c0 + tx * 2 + 1];
        *(float2*)&outp[(i0 + ty * 2 + ia) * DMODEL + c0 + tx * 2] = o;
    }
}

extern "C" void kernel_launch(void* const* d_in, const int* in_sizes, int n_in,
                              void* d_out, int out_size, void* d_ws, size_t ws_size,
                              hipStream_t stream)
{
    const float* x   = (const float*)d_in[0];
    const float* pos = (const float*)d_in[1];
    const float* Wq  = (const float*)d_in[2];
    const float* Wk  = (const float*)d_in[3];
    const float* Wv  = (const float*)d_in[4];
    const float* Wo  = (const float*)d_in[5];
    const float* bo  = (const float*)d_in[6];
    float* out = (float*)d_out;
    float* ws  = (float*)d_ws;

    k_proj<<<dim3(8, 8, 3), dim3(16, 16), 0, stream>>>(x, Wq, Wk, Wv, ws);
    k_qw<<<dim3(128), dim3(256), 0, stream>>>(Wk, ws);
    k_content<<<dim3(8, 8, 8), dim3(16, 16), 0, stream>>>(ws);
    k_rpe_softmax<<<dim3(512), dim3(256), 0, stream>>>(pos, ws);
    k_av<<<dim3(16, 8), dim3(16, 16), 0, stream>>>(ws);
    k_out<<<dim3(8, 16), dim3(16, 16), 0, stream>>>(Wo, bo, ws, out);
}

// Round 3
// 155.554 us; speedup vs baseline: 1.2715x; 1.0732x over previous
//
#include <hip/hip_runtime.h>
#include <math.h>

#define NQ      512
#define DMODEL  256
#define DINNER  512
#define NH      8
#define DHEAD   64
#define SCALE   0.125f
#define PI_F    3.14159265358979323846f

// workspace layout (float offsets)
#define Q_OFF   0           // 512*512
#define KC_OFF  262144      // 512*512
#define V_OFF   524288      // 512*512
#define QW_OFF  786432      // 512*544  (per-head blocks of 68: [sx16|cx16|sy16|cy16|dxw|dyw|pad2])
#define IN_OFF  1064960     // 512*512
// total 1327104 floats = 5.3 MB

// ---------------------------------------------------------------- K1: q/kc/v
__global__ __launch_bounds__(256) void k_proj(
    const float* __restrict__ x, const float* __restrict__ Wq,
    const float* __restrict__ Wk, const float* __restrict__ Wv,
    float* __restrict__ ws)
{
    const int z = blockIdx.z;
    const float* W = (z == 0) ? Wq : (z == 1) ? Wk : Wv;
    float* out = ws + ((z == 0) ? Q_OFF : (z == 1) ? KC_OFF : V_OFF);

    __shared__ alignas(16) float Xs[32][68];
    __shared__ alignas(16) float Bs[32][64];

    const int tx = threadIdx.x, ty = threadIdx.y;
    const int tid = ty * 16 + tx;
    const int row0 = blockIdx.y * 64, col0 = blockIdx.x * 64;

    float acc[4][4] = {};

    for (int k0 = 0; k0 < DMODEL; k0 += 32) {
        {
            const int m = tid >> 2;
            const int kk0 = (tid & 3) * 8;
            const float* src = x + (row0 + m) * DMODEL + k0 + kk0;
            float4 a0 = *(const float4*)(src);
            float4 a1 = *(const float4*)(src + 4);
            Xs[kk0 + 0][m] = a0.x; Xs[kk0 + 1][m] = a0.y;
            Xs[kk0 + 2][m] = a0.z; Xs[kk0 + 3][m] = a0.w;
            Xs[kk0 + 4][m] = a1.x; Xs[kk0 + 5][m] = a1.y;
            Xs[kk0 + 6][m] = a1.z; Xs[kk0 + 7][m] = a1.w;
        }
        {
            const int kk = tid >> 3;
            const int n0 = (tid & 7) * 8;
            const float* src = W + (k0 + kk) * DINNER + col0 + n0;
            *(float4*)&Bs[kk][n0]     = *(const float4*)(src);
            *(float4*)&Bs[kk][n0 + 4] = *(const float4*)(src + 4);
        }
        __syncthreads();
        #pragma unroll
        for (int kk = 0; kk < 32; ++kk) {
            float4 a4 = *(const float4*)&Xs[kk][ty * 4];
            float4 b4 = *(const float4*)&Bs[kk][tx * 4];
            float a[4] = {a4.x, a4.y, a4.z, a4.w};
            float b[4] = {b4.x, b4.y, b4.z, b4.w};
            #pragma unroll
            for (int ia = 0; ia < 4; ++ia)
                #pragma unroll
                for (int ib = 0; ib < 4; ++ib)
                    acc[ia][ib] += a[ia] * b[ib];
        }
        __syncthreads();
    }
    #pragma unroll
    for (int ia = 0; ia < 4; ++ia) {
        float4 o = make_float4(acc[ia][0], acc[ia][1], acc[ia][2], acc[ia][3]);
        *(float4*)&out[(row0 + ty * 4 + ia) * DINNER + col0 + tx * 4] = o;
    }
}

// ------------------------------------------------- K1b: qW, per-head layout
// qW[i*544 + h*68 + p]; p: 0..15 sin_x, 16..31 cos_x, 32..47 sin_y,
// 48..63 cos_y, 64 dx-weight, 65 dy-weight. (SCALE folded in.)
__global__ __launch_bounds__(256) void k_qw(
    const float* __restrict__ Wk, float* __restrict__ ws)
{
    const float* q = ws + Q_OFF;
    float* qW = ws + QW_OFF;
    const int h  = blockIdx.x >> 4;          // 8 heads
    const int i0 = (blockIdx.x & 15) * 32;   // 16 row-tiles of 32

    __shared__ float WrT[64][67];            // [d][r], pad 67
    __shared__ alignas(16) float Qs[32][68]; // [m][d]
    const int tid = threadIdx.x;

    for (int idx = tid; idx < 66 * 64; idx += 256) {
        int r = idx >> 6, d = idx & 63;
        WrT[d][r] = Wk[(DMODEL + r) * DINNER + h * DHEAD + d];
    }
    for (int idx = tid; idx < 32 * 16; idx += 256) {
        int m = idx >> 4, dq = (idx & 15) * 4;
        *(float4*)&Qs[m][dq] = *(const float4*)&q[(i0 + m) * DINNER + h * DHEAD + dq];
    }
    __syncthreads();

    for (int idx = tid; idx < 32 * 66; idx += 256) {
        int m = idx / 66, r = idx - m * 66;
        float acc = 0.f;
        #pragma unroll
        for (int d0 = 0; d0 < 64; d0 += 4) {
            float4 qf = *(const float4*)&Qs[m][d0];
            acc += qf.x * WrT[d0 + 0][r] + qf.y * WrT[d0 + 1][r]
                 + qf.z * WrT[d0 + 2][r] + qf.w * WrT[d0 + 3][r];
        }
        // original r: 0..15 sinx, 16..31 cosx, 32 dx, 33..48 siny, 49..64 cosy, 65 dy
        int p = (r < 32) ? r : (r == 32) ? 64 : (r < 65) ? (r - 1) : 65;
        qW[(i0 + m) * 544 + h * 68 + p] = acc * SCALE;
    }
}

// -------- fused attention: content scores + RPE + online softmax + PV ------
__device__ __forceinline__ float rpe_eval(float2 pq, float2 pk, const float4* cw)
{
    float dxr = (pk.x - pq.x) * (1.0f / 51.0f);
    float dyr = (pk.y - pq.y) * (1.0f / 51.0f);
    float dx = dxr / (1.0f + fabsf(dxr));
    float dy = dyr / (1.0f + fabsf(dyr));
    float thx = dx * PI_F, dlx = dx * (PI_F * 7.0f / 15.0f);
    float thy = dy * PI_F, dly = dy * (PI_F * 7.0f / 15.0f);
    float sxa, cxa, sxb, cxb, sya, cya, syb, cyb;
    __sincosf(thx, &sxa, &cxa);
    __sincosf(thx + dlx, &sxb, &cxb);
    __sincosf(thy, &sya, &cya);
    __sincosf(thy + dly, &syb, &cyb);
    const float Kx = 2.0f * __cosf(dlx);
    const float Ky = 2.0f * __cosf(dly);
    float acc = 0.f;
    #pragma unroll
    for (int g = 0; g < 4; ++g) {
        float4 wsx = cw[g], wcx = cw[4 + g], wsy = cw[8 + g], wcy = cw[12 + g];
        #pragma unroll
        for (int k = 0; k < 4; ++k) {
            float a = (&wsx.x)[k], b = (&wcx.x)[k], c = (&wsy.x)[k], e = (&wcy.x)[k];
            acc += sxa * a + cxa * b + sya * c + cya * e;
            // Chebyshev advance: f_{b+1} = K*f_b - f_{b-1}
            float t;
            t = Kx * sxb - sxa; sxa = sxb; sxb = t;
            t = Kx * cxb - cxa; cxa = cxb; cxb = t;
            t = Ky * syb - sya; sya = syb; syb = t;
            t = Ky * cyb - cya; cya = cyb; cyb = t;
        }
    }
    float4 tw = cw[16];
    acc += dx * tw.x + dy * tw.y;
    return acc;
}

__device__ __forceinline__ float wave_max(float v)
{
    #pragma unroll
    for (int off = 32; off; off >>= 1) v = fmaxf(v, __shfl_xor(v, off));
    return v;
}
__device__ __forceinline__ float wave_sum(float v)
{
    #pragma unroll
    for (int off = 32; off; off >>= 1) v += __shfl_xor(v, off);
    return v;
}

__global__ __launch_bounds__(256) void k_attn(
    const float* __restrict__ pos, float* __restrict__ ws)
{
    const float* q  = ws + Q_OFF;
    const float* kc = ws + KC_OFF;
    const float* v  = ws + V_OFF;
    const float* qW = ws + QW_OFF;
    float* inner    = ws + IN_OFF;

    const int h  = blockIdx.x >> 6;        // 8 heads
    const int i0 = (blockIdx.x & 63) * 8;  // 64 row-tiles of 8
    const int tid = threadIdx.x;
    const int w = tid >> 6, l = tid & 63;
    const int iw = w * 2;                  // 2 rows per wave

    __shared__ alignas(16) float Qs[64][12];   // [d][row]
    __shared__ alignas(16) float qWs[8][68];   // per-row coeffs (float4 x17)
    __shared__ float2 posQs[8];
    __shared__ alignas(16) float Ks[64][68];   // [d][j]  (transposed)
    __shared__ alignas(16) float Vs[64][68];   // [j][d]
    __shared__ float2 posKs[64];
    __shared__ alignas(16) float Ps[8][68];    // attn weights per row

    if (tid < 128) {
        int m = tid >> 4, d4 = (tid & 15) * 4;
        float4 qv = *(const float4*)&q[(i0 + m) * DINNER + h * DHEAD + d4];
        Qs[d4 + 0][m] = qv.x; Qs[d4 + 1][m] = qv.y;
        Qs[d4 + 2][m] = qv.z; Qs[d4 + 3][m] = qv.w;
    }
    for (int idx = tid; idx < 8 * 68; idx += 256) {
        int m = idx / 68, c = idx - m * 68;
        qWs[m][c] = qW[(i0 + m) * 544 + h * 68 + c];
    }
    if (tid < 8) posQs[tid] = *(const float2*)&pos[(i0 + tid) * 2];

    float m0 = -1e30f, m1 = -1e30f;
    float ls0 = 0.f, ls1 = 0.f;
    float acc0 = 0.f, acc1 = 0.f;

    const float4* cw0 = (const float4*)&qWs[iw][0];
    const float4* cw1 = (const float4*)&qWs[iw + 1][0];

    for (int jt = 0; jt < 8; ++jt) {
        const int j0 = jt * 64;
        __syncthreads();   // protect Ks/Vs from previous tile's readers (+initial loads)
        {
            const int jj = tid >> 2, dg = (tid & 3) * 16;
            const float* sk = kc + (j0 + jj) * DINNER + h * DHEAD + dg;
            float4 a = *(const float4*)(sk),     b = *(const float4*)(sk + 4),
                   c = *(const float4*)(sk + 8), d = *(const float4*)(sk + 12);
            Ks[dg +  0][jj] = a.x; Ks[dg +  1][jj] = a.y; Ks[dg +  2][jj] = a.z; Ks[dg +  3][jj] = a.w;
            Ks[dg +  4][jj] = b.x; Ks[dg +  5][jj] = b.y; Ks[dg +  6][jj] = b.z; Ks[dg +  7][jj] = b.w;
            Ks[dg +  8][jj] = c.x; Ks[dg +  9][jj] = c.y; Ks[dg + 10][jj] = c.z; Ks[dg + 11][jj] = c.w;
            Ks[dg + 12][jj] = d.x; Ks[dg + 13][jj] = d.y; Ks[dg + 14][jj] = d.z; Ks[dg + 15][jj] = d.w;
            const float* sv = v + (j0 + jj) * DINNER + h * DHEAD + dg;
            *(float4*)&Vs[jj][dg +  0] = *(const float4*)(sv);
            *(float4*)&Vs[jj][dg +  4] = *(const float4*)(sv + 4);
            *(float4*)&Vs[jj][dg +  8] = *(const float4*)(sv + 8);
            *(float4*)&Vs[jj][dg + 12] = *(const float4*)(sv + 12);
            if (tid < 64) posKs[tid] = *(const float2*)&pos[(j0 + tid) * 2];
        }
        __syncthreads();

        // content scores for this wave's 2 rows, column l
        float s0 = 0.f, s1 = 0.f;
        #pragma unroll 8
        for (int d = 0; d < 64; ++d) {
            float kf = Ks[d][l];
            float2 q2 = *(const float2*)&Qs[d][iw];
            s0 += q2.x * kf;
            s1 += q2.y * kf;
        }
        s0 *= SCALE; s1 *= SCALE;

        // RPE contribution (qW pre-scaled)
        float2 pk = posKs[l];
        s0 += rpe_eval(posQs[iw],     pk, cw0);
        s1 += rpe_eval(posQs[iw + 1], pk, cw1);

        // online softmax, row 0
        {
            float mt = wave_max(s0);
            float mn = fmaxf(m0, mt);
            float rs = __expf(m0 - mn);
            float p  = __expf(s0 - mn);
            ls0 = ls0 * rs + wave_sum(p);
            acc0 *= rs;
            m0 = mn;
            Ps[iw][l] = p;
        }
        // row 1
        {
            float mt = wave_max(s1);
            float mn = fmaxf(m1, mt);
            float rs = __expf(m1 - mn);
            float p  = __expf(s1 - mn);
            ls1 = ls1 * rs + wave_sum(p);
            acc1 *= rs;
            m1 = mn;
            Ps[iw + 1][l] = p;
        }
        __syncthreads();

        // PV: acc[row][d=l] += sum_j P[row][j] * V[j][l]
        #pragma unroll
        for (int jg = 0; jg < 16; ++jg) {
            float4 p0 = *(const float4*)&Ps[iw][jg * 4];
            float4 p1 = *(const float4*)&Ps[iw + 1][jg * 4];
            float v0 = Vs[jg * 4 + 0][l];
            float v1 = Vs[jg * 4 + 1][l];
            float v2 = Vs[jg * 4 + 2][l];
            float v3 = Vs[jg * 4 + 3][l];
            acc0 += p0.x * v0 + p0.y * v1 + p0.z * v2 + p0.w * v3;
            acc1 += p1.x * v0 + p1.y * v1 + p1.z * v2 + p1.w * v3;
        }
    }

    inner[(i0 + iw)     * DINNER + h * DHEAD + l] = acc0 / ls0;
    inner[(i0 + iw + 1) * DINNER + h * DHEAD + l] = acc1 / ls1;
}

// ------------------------------------------------ K5: out = inner @ Wo + bo
__global__ __launch_bounds__(256) void k_out(
    const float* __restrict__ Wo, const float* __restrict__ bo,
    float* __restrict__ ws, float* __restrict__ outp)
{
    const float* inner = ws + IN_OFF;
    const int c0 = blockIdx.x * 32;
    const int i0 = blockIdx.y * 32;

    __shared__ alignas(16) float Xs[32][36];   // [kk][m]
    __shared__ alignas(16) float Bs[32][32];   // [kk][n]
    const int tx = threadIdx.x, ty = threadIdx.y;
    const int tid = ty * 16 + tx;

    float acc[2][2] = {};
    for (int k0 = 0; k0 < DINNER; k0 += 32) {
        {
            const int m = tid >> 3;
            const int kk0 = (tid & 7) * 4;
            float4 a4 = *(const float4*)&inner[(i0 + m) * DINNER + k0 + kk0];
            Xs[kk0 + 0][m] = a4.x; Xs[kk0 + 1][m] = a4.y;
            Xs[kk0 + 2][m] = a4.z; Xs[kk0 + 3][m] = a4.w;
        }
        {
            const int kk = tid >> 3;
            const int n0 = (tid & 7) * 4;
            *(float4*)&Bs[kk][n0] = *(const float4*)&Wo[(k0 + kk) * DMODEL + c0 + n0];
        }
        __syncthreads();
        #pragma unroll
        for (int kk = 0; kk < 32; ++kk) {
            float2 a2 = *(const float2*)&Xs[kk][ty * 2];
            float2 b2 = *(const float2*)&Bs[kk][tx * 2];
            acc[0][0] += a2.x * b2.x;
            acc[0][1] += a2.x * b2.y;
            acc[1][0] += a2.y * b2.x;
            acc[1][1] += a2.y * b2.y;
        }
        __syncthreads();
    }
    #pragma unroll
    for (int ia = 0; ia < 2; ++ia) {
        float2 o;
        o.x = acc[ia][0] + bo[c0 + tx * 2 + 0];
        o.y = acc[ia][1] + bo[c0 + tx * 2 + 1];
        *(float2*)&outp[(i0 + ty * 2 + ia) * DMODEL + c0 + tx * 2] = o;
    }
}

extern "C" void kernel_launch(void* const* d_in, const int* in_sizes, int n_in,
                              void* d_out, int out_size, void* d_ws, size_t ws_size,
                              hipStream_t stream)
{
    const float* x   = (const float*)d_in[0];
    const float* pos = (const float*)d_in[1];
    const float* Wq  = (const float*)d_in[2];
    const float* Wk  = (const float*)d_in[3];
    const float* Wv  = (const float*)d_in[4];
    const float* Wo  = (const float*)d_in[5];
    const float* bo  = (const float*)d_in[6];
    float* out = (float*)d_out;
    float* ws  = (float*)d_ws;

    k_proj<<<dim3(8, 8, 3), dim3(16, 16), 0, stream>>>(x, Wq, Wk, Wv, ws);
    k_qw<<<dim3(128), dim3(256), 0, stream>>>(Wk, ws);
    k_attn<<<dim3(512), dim3(256), 0, stream>>>(pos, ws);
    k_out<<<dim3(8, 16), dim3(16, 16), 0, stream>>>(Wo, bo, ws, out);
}

// Round 7
// 146.658 us; speedup vs baseline: 1.3486x; 1.0607x over previous
//
#include <hip/hip_runtime.h>
#include <math.h>

#define NQ      512
#define DMODEL  256
#define DINNER  512
#define NH      8
#define DHEAD   64
#define SCALE   0.125f
#define PI_F    3.14159265358979323846f

// workspace layout (float offsets)
#define Q_OFF   0           // 512*512
#define KC_OFF  262144      // 512*512
#define V_OFF   524288      // 512*512
#define QW_OFF  786432      // 512*544 (per-head blocks of 68)
#define IN_OFF  1064960     // 512*512
#define PA_OFF  1327104     // 4096*8*64 partial accs
#define PM_OFF  3424256     // 4096*8 partial maxes
#define PL_OFF  3457024     // 4096*8 partial sums
// total 3489792 floats = 14.0 MB

// ---------------------------------------------------------------- K1: q/kc/v
__global__ __launch_bounds__(256) void k_proj(
    const float* __restrict__ x, const float* __restrict__ Wq,
    const float* __restrict__ Wk, const float* __restrict__ Wv,
    float* __restrict__ ws)
{
    const int z = blockIdx.z;
    const float* W = (z == 0) ? Wq : (z == 1) ? Wk : Wv;
    float* out = ws + ((z == 0) ? Q_OFF : (z == 1) ? KC_OFF : V_OFF);

    __shared__ alignas(16) float Xs[32][68];
    __shared__ alignas(16) float Bs[32][64];

    const int tx = threadIdx.x, ty = threadIdx.y;
    const int tid = ty * 16 + tx;
    const int row0 = blockIdx.y * 64, col0 = blockIdx.x * 64;

    float acc[4][4] = {};

    for (int k0 = 0; k0 < DMODEL; k0 += 32) {
        {
            const int m = tid >> 2;
            const int kk0 = (tid & 3) * 8;
            const float* src = x + (row0 + m) * DMODEL + k0 + kk0;
            float4 a0 = *(const float4*)(src);
            float4 a1 = *(const float4*)(src + 4);
            Xs[kk0 + 0][m] = a0.x; Xs[kk0 + 1][m] = a0.y;
            Xs[kk0 + 2][m] = a0.z; Xs[kk0 + 3][m] = a0.w;
            Xs[kk0 + 4][m] = a1.x; Xs[kk0 + 5][m] = a1.y;
            Xs[kk0 + 6][m] = a1.z; Xs[kk0 + 7][m] = a1.w;
        }
        {
            const int kk = tid >> 3;
            const int n0 = (tid & 7) * 8;
            const float* src = W + (k0 + kk) * DINNER + col0 + n0;
            *(float4*)&Bs[kk][n0]     = *(const float4*)(src);
            *(float4*)&Bs[kk][n0 + 4] = *(const float4*)(src + 4);
        }
        __syncthreads();
        #pragma unroll
        for (int kk = 0; kk < 32; ++kk) {
            float4 a4 = *(const float4*)&Xs[kk][ty * 4];
            float4 b4 = *(const float4*)&Bs[kk][tx * 4];
            float a[4] = {a4.x, a4.y, a4.z, a4.w};
            float b[4] = {b4.x, b4.y, b4.z, b4.w};
            #pragma unroll
            for (int ia = 0; ia < 4; ++ia)
                #pragma unroll
                for (int ib = 0; ib < 4; ++ib)
                    acc[ia][ib] += a[ia] * b[ib];
        }
        __syncthreads();
    }
    #pragma unroll
    for (int ia = 0; ia < 4; ++ia) {
        float4 o = make_float4(acc[ia][0], acc[ia][1], acc[ia][2], acc[ia][3]);
        *(float4*)&out[(row0 + ty * 4 + ia) * DINNER + col0 + tx * 4] = o;
    }
}

// ------------------------------------------------- K1b: qW, per-head layout
// qW[i*544 + h*68 + p]; p: 0..15 sin_x, 16..31 cos_x, 32..47 sin_y,
// 48..63 cos_y, 64 dx-weight, 65 dy-weight. (SCALE folded in.)
__global__ __launch_bounds__(256) void k_qw(
    const float* __restrict__ Wk, float* __restrict__ ws)
{
    const float* q = ws + Q_OFF;
    float* qW = ws + QW_OFF;
    const int h  = blockIdx.x >> 4;          // 8 heads
    const int i0 = (blockIdx.x & 15) * 32;   // 16 row-tiles of 32

    __shared__ float WrT[64][67];            // [d][r], pad 67
    __shared__ alignas(16) float Qs[32][68]; // [m][d]
    const int tid = threadIdx.x;

    for (int idx = tid; idx < 66 * 64; idx += 256) {
        int r = idx >> 6, d = idx & 63;
        WrT[d][r] = Wk[(DMODEL + r) * DINNER + h * DHEAD + d];
    }
    for (int idx = tid; idx < 32 * 16; idx += 256) {
        int m = idx >> 4, dq = (idx & 15) * 4;
        *(float4*)&Qs[m][dq] = *(const float4*)&q[(i0 + m) * DINNER + h * DHEAD + dq];
    }
    __syncthreads();

    for (int idx = tid; idx < 32 * 66; idx += 256) {
        int m = idx / 66, r = idx - m * 66;
        float acc = 0.f;
        #pragma unroll
        for (int d0 = 0; d0 < 64; d0 += 4) {
            float4 qf = *(const float4*)&Qs[m][d0];
            acc += qf.x * WrT[d0 + 0][r] + qf.y * WrT[d0 + 1][r]
                 + qf.z * WrT[d0 + 2][r] + qf.w * WrT[d0 + 3][r];
        }
        // original r: 0..15 sinx, 16..31 cosx, 32 dx, 33..48 siny, 49..64 cosy, 65 dy
        int p = (r < 32) ? r : (r == 32) ? 64 : (r < 65) ? (r - 1) : 65;
        qW[(i0 + m) * 544 + h * 68 + p] = acc * SCALE;
    }
}

// --------- fused attention v2: lane = query row; K/V broadcast from LDS ----
// grid (jsuper 8, itile 8, head 8); 256 thr; wave w handles 16 j's.
// Per lane: Q row + qW coeffs in regs, full softmax per-lane, acc[64] in regs.
// 4-wave intra-block merge in LDS; cross-block merge via partials + k_merge.
__global__ __launch_bounds__(256, 2) void k_attn(
    const float* __restrict__ pos, float* __restrict__ ws)
{
    const float* q  = ws + Q_OFF;
    const float* kc = ws + KC_OFF;
    const float* v  = ws + V_OFF;
    const float* qW = ws + QW_OFF;
    float* pacc = ws + PA_OFF;
    float* pm   = ws + PM_OFF;
    float* pl   = ws + PL_OFF;

    const int c  = blockIdx.x;             // jsuper 0..7
    const int it = blockIdx.y;             // itile 0..7
    const int h  = blockIdx.z;             // head
    const int tid = threadIdx.x;
    const int w = tid >> 6, l = tid & 63;
    const int i = it * 64 + l;             // this lane's query row
    const int j0 = c * 64;                 // block j-range

    __shared__ alignas(16) float Ks[64][68];
    __shared__ alignas(16) float Vs[64][68];
    __shared__ float2 posKs[64];
    __shared__ float pmL[4][64];
    __shared__ float plL[4][64];

    // stage K/V rows j0..j0+63 (coalesced global, once per block)
    {
        const int jj = tid >> 2, dg = (tid & 3) * 16;
        const float* sk = kc + (j0 + jj) * DINNER + h * DHEAD + dg;
        *(float4*)&Ks[jj][dg +  0] = *(const float4*)(sk);
        *(float4*)&Ks[jj][dg +  4] = *(const float4*)(sk + 4);
        *(float4*)&Ks[jj][dg +  8] = *(const float4*)(sk + 8);
        *(float4*)&Ks[jj][dg + 12] = *(const float4*)(sk + 12);
        const float* sv = v + (j0 + jj) * DINNER + h * DHEAD + dg;
        *(float4*)&Vs[jj][dg +  0] = *(const float4*)(sv);
        *(float4*)&Vs[jj][dg +  4] = *(const float4*)(sv + 4);
        *(float4*)&Vs[jj][dg +  8] = *(const float4*)(sv + 8);
        *(float4*)&Vs[jj][dg + 12] = *(const float4*)(sv + 12);
        if (tid < 64) posKs[tid] = *(const float2*)&pos[(j0 + tid) * 2];
    }

    // per-lane register loads (own row; once per kernel)
    float4 qv[16];
    const float* qrow = q + i * DINNER + h * DHEAD;
    #pragma unroll
    for (int d4 = 0; d4 < 16; ++d4) qv[d4] = *(const float4*)(qrow + d4 * 4);
    float4 cw[17];
    const float* qwrow = qW + i * 544 + h * 68;
    #pragma unroll
    for (int p4 = 0; p4 < 17; ++p4) cw[p4] = *(const float4*)(qwrow + p4 * 4);
    const float2 pq = *(const float2*)&pos[i * 2];

    __syncthreads();

    const int jb = w * 16;
    float sreg[16];
    float M = -1e30f;

    #pragma unroll
    for (int t = 0; t < 16; ++t) {
        const int jr = jb + t;
        // content dot: K row broadcast (uniform addr), Q in regs
        float s0 = 0.f, s1 = 0.f, s2 = 0.f, s3 = 0.f;
        #pragma unroll
        for (int d4 = 0; d4 < 16; ++d4) {
            float4 kv = *(const float4*)&Ks[jr][d4 * 4];
            s0 += qv[d4].x * kv.x; s1 += qv[d4].y * kv.y;
            s2 += qv[d4].z * kv.z; s3 += qv[d4].w * kv.w;
        }
        float s = (s0 + s1) + (s2 + s3);

        // RPE: per-lane features (Chebyshev ladder), coeffs in regs
        float2 pk = posKs[jr];
        float dxr = (pk.x - pq.x) * (1.0f / 51.0f);
        float dyr = (pk.y - pq.y) * (1.0f / 51.0f);
        float dx = __fdividef(dxr, 1.0f + fabsf(dxr));
        float dy = __fdividef(dyr, 1.0f + fabsf(dyr));
        float thx = dx * PI_F, dlx = dx * (PI_F * 7.0f / 15.0f);
        float thy = dy * PI_F, dly = dy * (PI_F * 7.0f / 15.0f);
        float sxa, cxa, sxb, cxb, sya, cya, syb, cyb;
        __sincosf(thx,       &sxa, &cxa);
        __sincosf(thx + dlx, &sxb, &cxb);
        __sincosf(thy,       &sya, &cya);
        __sincosf(thy + dly, &syb, &cyb);
        float Kx = 2.0f * (cxa * cxb + sxa * sxb);   // 2*cos(dlx)
        float Ky = 2.0f * (cya * cyb + sya * syb);   // 2*cos(dly)
        float r0 = 0.f, r1 = 0.f, r2 = 0.f, r3 = 0.f;
        #pragma unroll
        for (int g = 0; g < 4; ++g) {
            float4 wsx = cw[g], wcx = cw[4 + g], wsy = cw[8 + g], wcy = cw[12 + g];
            #pragma unroll
            for (int k = 0; k < 4; ++k) {
                r0 += sxa * (&wsx.x)[k];
                r1 += cxa * (&wcx.x)[k];
                r2 += sya * (&wsy.x)[k];
                r3 += cya * (&wcy.x)[k];
                float tt;
                tt = Kx * sxb - sxa; sxa = sxb; sxb = tt;
                tt = Kx * cxb - cxa; cxa = cxb; cxb = tt;
                tt = Ky * syb - sya; sya = syb; syb = tt;
                tt = Ky * cyb - cya; cya = cyb; cyb = tt;
            }
        }
        float rpe = (r0 + r1) + (r2 + r3) + dx * cw[16].x + dy * cw[16].y;
        float score = s * SCALE + rpe;
        sreg[t] = score;
        M = fmaxf(M, score);
    }

    // single-pass softmax over this wave's 16-j chunk + PV accumulate
    float4 av[16];
    #pragma unroll
    for (int d4 = 0; d4 < 16; ++d4) av[d4] = make_float4(0.f, 0.f, 0.f, 0.f);
    float lsum = 0.f;
    #pragma unroll
    for (int t = 0; t < 16; ++t) {
        float p = __expf(sreg[t] - M);
        lsum += p;
        const int jr = jb + t;
        #pragma unroll
        for (int d4 = 0; d4 < 16; ++d4) {
            float4 vv = *(const float4*)&Vs[jr][d4 * 4];
            av[d4].x += p * vv.x; av[d4].y += p * vv.y;
            av[d4].z += p * vv.z; av[d4].w += p * vv.w;
        }
    }

    // ---- intra-block merge of 4 waves (same (h,i), different j-quarters) ----
    pmL[w][l] = M; plL[w][l] = lsum;
    __syncthreads();
    float m0 = pmL[0][l], m1 = pmL[1][l], m2 = pmL[2][l], m3 = pmL[3][l];
    float Mg = fmaxf(fmaxf(m0, m1), fmaxf(m2, m3));
    float e = __expf(M - Mg);
    #pragma unroll
    for (int d4 = 0; d4 < 16; ++d4) {
        av[d4].x *= e; av[d4].y *= e; av[d4].z *= e; av[d4].w *= e;
    }
    float (*Sacc)[68] = Ks;   // reuse Ks (all reads done)
    if (w == 0) {
        #pragma unroll
        for (int d4 = 0; d4 < 16; ++d4) *(float4*)&Sacc[l][d4 * 4] = av[d4];
    }
    __syncthreads();
    if (w == 1) {
        #pragma unroll
        for (int d4 = 0; d4 < 16; ++d4) {
            float4 sv = *(const float4*)&Sacc[l][d4 * 4];
            sv.x += av[d4].x; sv.y += av[d4].y; sv.z += av[d4].z; sv.w += av[d4].w;
            *(float4*)&Sacc[l][d4 * 4] = sv;
        }
    }
    __syncthreads();
    if (w == 2) {
        #pragma unroll
        for (int d4 = 0; d4 < 16; ++d4) {
            float4 sv = *(const float4*)&Sacc[l][d4 * 4];
            sv.x += av[d4].x; sv.y += av[d4].y; sv.z += av[d4].z; sv.w += av[d4].w;
            *(float4*)&Sacc[l][d4 * 4] = sv;
        }
    }
    __syncthreads();
    if (w == 3) {
        float Lg = plL[0][l] * __expf(m0 - Mg) + plL[1][l] * __expf(m1 - Mg)
                 + plL[2][l] * __expf(m2 - Mg) + plL[3][l] * __expf(m3 - Mg);
        float* prow = pacc + ((size_t)((h * NQ + i) * 8 + c)) * 64;
        #pragma unroll
        for (int d4 = 0; d4 < 16; ++d4) {
            float4 sv = *(const float4*)&Sacc[l][d4 * 4];
            sv.x += av[d4].x; sv.y += av[d4].y; sv.z += av[d4].z; sv.w += av[d4].w;
            *(float4*)&prow[d4 * 4] = sv;
        }
        pm[(h * NQ + i) * 8 + c] = Mg;
        pl[(h * NQ + i) * 8 + c] = Lg;
    }
}

// --------------- cross-block merge of 8 partials -> inner -------------------
__global__ __launch_bounds__(256) void k_merge(float* __restrict__ ws)
{
    float* inner      = ws + IN_OFF;
    const float* pacc = ws + PA_OFF;
    const float* pm   = ws + PM_OFF;
    const float* pl   = ws + PL_OFF;

    const int g = blockIdx.x * 4 + (threadIdx.x >> 6);  // (h,i) row, 0..4095
    const int l = threadIdx.x & 63;                     // d

    float mv[8];
    #pragma unroll
    for (int cc = 0; cc < 8; ++cc) mv[cc] = pm[g * 8 + cc];
    float Mg = mv[0];
    #pragma unroll
    for (int cc = 1; cc < 8; ++cc) Mg = fmaxf(Mg, mv[cc]);
    float L = 0.f, a = 0.f;
    #pragma unroll
    for (int cc = 0; cc < 8; ++cc) {
        float e = __expf(mv[cc] - Mg);
        L += pl[g * 8 + cc] * e;
        a += pacc[(size_t)(g * 8 + cc) * 64 + l] * e;
    }
    const int h = g >> 9, i = g & 511;
    inner[i * DINNER + h * DHEAD + l] = a / L;
}

// ------------------------------------------------ K5: out = inner @ Wo + bo
__global__ __launch_bounds__(256) void k_out(
    const float* __restrict__ Wo, const float* __restrict__ bo,
    float* __restrict__ ws, float* __restrict__ outp)
{
    const float* inner = ws + IN_OFF;
    const int c0 = blockIdx.x * 32;
    const int i0 = blockIdx.y * 32;

    __shared__ alignas(16) float Xs[32][36];   // [kk][m]
    __shared__ alignas(16) float Bs[32][32];   // [kk][n]
    const int tx = threadIdx.x, ty = threadIdx.y;
    const int tid = ty * 16 + tx;

    float acc[2][2] = {};
    for (int k0 = 0; k0 < DINNER; k0 += 32) {
        {
            const int m = tid >> 3;
            const int kk0 = (tid & 7) * 4;
            float4 a4 = *(const float4*)&inner[(i0 + m) * DINNER + k0 + kk0];
            Xs[kk0 + 0][m] = a4.x; Xs[kk0 + 1][m] = a4.y;
            Xs[kk0 + 2][m] = a4.z; Xs[kk0 + 3][m] = a4.w;
        }
        {
            const int kk = tid >> 3;
            const int n0 = (tid & 7) * 4;
            *(float4*)&Bs[kk][n0] = *(const float4*)&Wo[(k0 + kk) * DMODEL + c0 + n0];
        }
        __syncthreads();
        #pragma unroll
        for (int kk = 0; kk < 32; ++kk) {
            float2 a2 = *(const float2*)&Xs[kk][ty * 2];
            float2 b2 = *(const float2*)&Bs[kk][tx * 2];
            acc[0][0] += a2.x * b2.x;
            acc[0][1] += a2.x * b2.y;
            acc[1][0] += a2.y * b2.x;
            acc[1][1] += a2.y * b2.y;
        }
        __syncthreads();
    }
    #pragma unroll
    for (int ia = 0; ia < 2; ++ia) {
        float2 o;
        o.x = acc[ia][0] + bo[c0 + tx * 2 + 0];
        o.y = acc[ia][1] + bo[c0 + tx * 2 + 1];
        *(float2*)&outp[(i0 + ty * 2 + ia) * DMODEL + c0 + tx * 2] = o;
    }
}

extern "C" void kernel_launch(void* const* d_in, const int* in_sizes, int n_in,
                              void* d_out, int out_size, void* d_ws, size_t ws_size,
                              hipStream_t stream)
{
    const float* x   = (const float*)d_in[0];
    const float* pos = (const float*)d_in[1];
    const float* Wq  = (const float*)d_in[2];
    const float* Wk  = (const float*)d_in[3];
    const float* Wv  = (const float*)d_in[4];
    const float* Wo  = (const float*)d_in[5];
    const float* bo  = (const float*)d_in[6];
    float* out = (float*)d_out;
    float* ws  = (float*)d_ws;

    k_proj<<<dim3(8, 8, 3), dim3(16, 16), 0, stream>>>(x, Wq, Wk, Wv, ws);
    k_qw<<<dim3(128), dim3(256), 0, stream>>>(Wk, ws);
    k_attn<<<dim3(8, 8, 8), dim3(256), 0, stream>>>(pos, ws);
    k_merge<<<dim3(1024), dim3(256), 0, stream>>>(ws);
    k_out<<<dim3(8, 16), dim3(16, 16), 0, stream>>>(Wo, bo, ws, out);
}

// Round 9
// 146.356 us; speedup vs baseline: 1.3514x; 1.0021x over previous
//
#include <hip/hip_runtime.h>
#include <math.h>

#define NQ      512
#define DMODEL  256
#define DINNER  512
#define NH      8
#define DHEAD   64
#define SCALE   0.125f
#define PI_F    3.14159265358979323846f

// workspace layout (float offsets)
#define Q_OFF   0           // 512*512
#define KC_OFF  262144      // 512*512
#define V_OFF   524288      // 512*512
#define QW_OFF  786432      // 512*544 (per-head blocks of 68)
#define IN_OFF  1064960     // 512*512
#define PA_OFF  1327104     // 4096*8*64 partial accs
#define PM_OFF  3424256     // 4096*8 partial maxes
#define PL_OFF  3457024     // 4096*8 partial sums
// total 3489792 floats = 14.0 MB

// ---------------------------------------------------------------- K1: q/kc/v
__global__ __launch_bounds__(256) void k_proj(
    const float* __restrict__ x, const float* __restrict__ Wq,
    const float* __restrict__ Wk, const float* __restrict__ Wv,
    float* __restrict__ ws)
{
    const int z = blockIdx.z;
    const float* W = (z == 0) ? Wq : (z == 1) ? Wk : Wv;
    float* out = ws + ((z == 0) ? Q_OFF : (z == 1) ? KC_OFF : V_OFF);

    __shared__ alignas(16) float Xs[32][68];
    __shared__ alignas(16) float Bs[32][64];

    const int tx = threadIdx.x, ty = threadIdx.y;
    const int tid = ty * 16 + tx;
    const int row0 = blockIdx.y * 64, col0 = blockIdx.x * 64;

    float acc[4][4] = {};

    for (int k0 = 0; k0 < DMODEL; k0 += 32) {
        {
            const int m = tid >> 2;
            const int kk0 = (tid & 3) * 8;
            const float* src = x + (row0 + m) * DMODEL + k0 + kk0;
            float4 a0 = *(const float4*)(src);
            float4 a1 = *(const float4*)(src + 4);
            Xs[kk0 + 0][m] = a0.x; Xs[kk0 + 1][m] = a0.y;
            Xs[kk0 + 2][m] = a0.z; Xs[kk0 + 3][m] = a0.w;
            Xs[kk0 + 4][m] = a1.x; Xs[kk0 + 5][m] = a1.y;
            Xs[kk0 + 6][m] = a1.z; Xs[kk0 + 7][m] = a1.w;
        }
        {
            const int kk = tid >> 3;
            const int n0 = (tid & 7) * 8;
            const float* src = W + (k0 + kk) * DINNER + col0 + n0;
            *(float4*)&Bs[kk][n0]     = *(const float4*)(src);
            *(float4*)&Bs[kk][n0 + 4] = *(const float4*)(src + 4);
        }
        __syncthreads();
        #pragma unroll
        for (int kk = 0; kk < 32; ++kk) {
            float4 a4 = *(const float4*)&Xs[kk][ty * 4];
            float4 b4 = *(const float4*)&Bs[kk][tx * 4];
            float a[4] = {a4.x, a4.y, a4.z, a4.w};
            float b[4] = {b4.x, b4.y, b4.z, b4.w};
            #pragma unroll
            for (int ia = 0; ia < 4; ++ia)
                #pragma unroll
                for (int ib = 0; ib < 4; ++ib)
                    acc[ia][ib] += a[ia] * b[ib];
        }
        __syncthreads();
    }
    #pragma unroll
    for (int ia = 0; ia < 4; ++ia) {
        float4 o = make_float4(acc[ia][0], acc[ia][1], acc[ia][2], acc[ia][3]);
        *(float4*)&out[(row0 + ty * 4 + ia) * DINNER + col0 + tx * 4] = o;
    }
}

// ------------------------------------------------- K1b: qW, per-head layout
// qW[i*544 + h*68 + p]; p: 0..15 sin_x, 16..31 cos_x, 32..47 sin_y,
// 48..63 cos_y, 64 dx-weight, 65 dy-weight. (SCALE folded in.)
__global__ __launch_bounds__(256) void k_qw(
    const float* __restrict__ Wk, float* __restrict__ ws)
{
    const float* q = ws + Q_OFF;
    float* qW = ws + QW_OFF;
    const int h  = blockIdx.x >> 4;          // 8 heads
    const int i0 = (blockIdx.x & 15) * 32;   // 16 row-tiles of 32

    __shared__ float WrT[64][67];            // [d][r], pad 67
    __shared__ alignas(16) float Qs[32][68]; // [m][d]
    const int tid = threadIdx.x;

    for (int idx = tid; idx < 66 * 64; idx += 256) {
        int r = idx >> 6, d = idx & 63;
        WrT[d][r] = Wk[(DMODEL + r) * DINNER + h * DHEAD + d];
    }
    for (int idx = tid; idx < 32 * 16; idx += 256) {
        int m = idx >> 4, dq = (idx & 15) * 4;
        *(float4*)&Qs[m][dq] = *(const float4*)&q[(i0 + m) * DINNER + h * DHEAD + dq];
    }
    __syncthreads();

    for (int idx = tid; idx < 32 * 66; idx += 256) {
        int m = idx / 66, r = idx - m * 66;
        float acc = 0.f;
        #pragma unroll
        for (int d0 = 0; d0 < 64; d0 += 4) {
            float4 qf = *(const float4*)&Qs[m][d0];
            acc += qf.x * WrT[d0 + 0][r] + qf.y * WrT[d0 + 1][r]
                 + qf.z * WrT[d0 + 2][r] + qf.w * WrT[d0 + 3][r];
        }
        // original r: 0..15 sinx, 16..31 cosx, 32 dx, 33..48 siny, 49..64 cosy, 65 dy
        int p = (r < 32) ? r : (r == 32) ? 64 : (r < 65) ? (r - 1) : 65;
        qW[(i0 + m) * 544 + h * 68 + p] = acc * SCALE;
    }
}

// --------- fused attention v2.1: lane = query row; K/V broadcast from LDS --
// Identical structure to v2; RPE band loop hand-unrolled with explicit
// .x/.y/.z/.w member reads (no (&f4.x)[k] address-of-member indexing, which
// forced qv/cw/av into scratch: VGPR_Count was 80, should be ~230).
#define BAND_STEP(WSX, WCX, WSY, WCY)                              \
    r0 += sxa * (WSX); r1 += cxa * (WCX);                          \
    r2 += sya * (WSY); r3 += cya * (WCY);                          \
    {   float tt;                                                  \
        tt = Kx * sxb - sxa; sxa = sxb; sxb = tt;                  \
        tt = Kx * cxb - cxa; cxa = cxb; cxb = tt;                  \
        tt = Ky * syb - sya; sya = syb; syb = tt;                  \
        tt = Ky * cyb - cya; cya = cyb; cyb = tt; }

__global__ __launch_bounds__(256, 2) void k_attn(
    const float* __restrict__ pos, float* __restrict__ ws)
{
    const float* q  = ws + Q_OFF;
    const float* kc = ws + KC_OFF;
    const float* v  = ws + V_OFF;
    const float* qW = ws + QW_OFF;
    float* pacc = ws + PA_OFF;
    float* pm   = ws + PM_OFF;
    float* pl   = ws + PL_OFF;

    const int c  = blockIdx.x;             // jsuper 0..7
    const int it = blockIdx.y;             // itile 0..7
    const int h  = blockIdx.z;             // head
    const int tid = threadIdx.x;
    const int w = tid >> 6, l = tid & 63;
    const int i = it * 64 + l;             // this lane's query row
    const int j0 = c * 64;                 // block j-range

    __shared__ alignas(16) float Ks[64][68];
    __shared__ alignas(16) float Vs[64][68];
    __shared__ float2 posKs[64];
    __shared__ float pmL[4][64];
    __shared__ float plL[4][64];

    // stage K/V rows j0..j0+63 (coalesced global, once per block)
    {
        const int jj = tid >> 2, dg = (tid & 3) * 16;
        const float* sk = kc + (j0 + jj) * DINNER + h * DHEAD + dg;
        *(float4*)&Ks[jj][dg +  0] = *(const float4*)(sk);
        *(float4*)&Ks[jj][dg +  4] = *(const float4*)(sk + 4);
        *(float4*)&Ks[jj][dg +  8] = *(const float4*)(sk + 8);
        *(float4*)&Ks[jj][dg + 12] = *(const float4*)(sk + 12);
        const float* sv = v + (j0 + jj) * DINNER + h * DHEAD + dg;
        *(float4*)&Vs[jj][dg +  0] = *(const float4*)(sv);
        *(float4*)&Vs[jj][dg +  4] = *(const float4*)(sv + 4);
        *(float4*)&Vs[jj][dg +  8] = *(const float4*)(sv + 8);
        *(float4*)&Vs[jj][dg + 12] = *(const float4*)(sv + 12);
        if (tid < 64) posKs[tid] = *(const float2*)&pos[(j0 + tid) * 2];
    }

    // per-lane register loads (own row; once per kernel)
    float4 qv[16];
    const float* qrow = q + i * DINNER + h * DHEAD;
    #pragma unroll
    for (int d4 = 0; d4 < 16; ++d4) qv[d4] = *(const float4*)(qrow + d4 * 4);
    float4 cw[17];
    const float* qwrow = qW + i * 544 + h * 68;
    #pragma unroll
    for (int p4 = 0; p4 < 17; ++p4) cw[p4] = *(const float4*)(qwrow + p4 * 4);
    const float2 pq = *(const float2*)&pos[i * 2];

    __syncthreads();

    const int jb = w * 16;
    float sreg[16];
    float M = -1e30f;

    #pragma unroll
    for (int t = 0; t < 16; ++t) {
        const int jr = jb + t;
        // content dot: K row broadcast (uniform addr), Q in regs
        float s0 = 0.f, s1 = 0.f, s2 = 0.f, s3 = 0.f;
        #pragma unroll
        for (int d4 = 0; d4 < 16; ++d4) {
            float4 kv = *(const float4*)&Ks[jr][d4 * 4];
            s0 += qv[d4].x * kv.x; s1 += qv[d4].y * kv.y;
            s2 += qv[d4].z * kv.z; s3 += qv[d4].w * kv.w;
        }
        float s = (s0 + s1) + (s2 + s3);

        // RPE: per-lane features (Chebyshev ladder), coeffs in regs
        float2 pk = posKs[jr];
        float dxr = (pk.x - pq.x) * (1.0f / 51.0f);
        float dyr = (pk.y - pq.y) * (1.0f / 51.0f);
        float dx = __fdividef(dxr, 1.0f + fabsf(dxr));
        float dy = __fdividef(dyr, 1.0f + fabsf(dyr));
        float thx = dx * PI_F, dlx = dx * (PI_F * 7.0f / 15.0f);
        float thy = dy * PI_F, dly = dy * (PI_F * 7.0f / 15.0f);
        float sxa, cxa, sxb, cxb, sya, cya, syb, cyb;
        __sincosf(thx,       &sxa, &cxa);
        __sincosf(thx + dlx, &sxb, &cxb);
        __sincosf(thy,       &sya, &cya);
        __sincosf(thy + dly, &syb, &cyb);
        float Kx = 2.0f * (cxa * cxb + sxa * sxb);   // 2*cos(dlx)
        float Ky = 2.0f * (cya * cyb + sya * syb);   // 2*cos(dly)
        float r0 = 0.f, r1 = 0.f, r2 = 0.f, r3 = 0.f;
        #pragma unroll
        for (int g = 0; g < 4; ++g) {
            float4 wsx = cw[g], wcx = cw[4 + g], wsy = cw[8 + g], wcy = cw[12 + g];
            BAND_STEP(wsx.x, wcx.x, wsy.x, wcy.x)
            BAND_STEP(wsx.y, wcx.y, wsy.y, wcy.y)
            BAND_STEP(wsx.z, wcx.z, wsy.z, wcy.z)
            BAND_STEP(wsx.w, wcx.w, wsy.w, wcy.w)
        }
        float rpe = (r0 + r1) + (r2 + r3) + dx * cw[16].x + dy * cw[16].y;
        float score = s * SCALE + rpe;
        sreg[t] = score;
        M = fmaxf(M, score);
    }

    // single-pass softmax over this wave's 16-j chunk + PV accumulate
    float4 av[16];
    #pragma unroll
    for (int d4 = 0; d4 < 16; ++d4) av[d4] = make_float4(0.f, 0.f, 0.f, 0.f);
    float lsum = 0.f;
    #pragma unroll
    for (int t = 0; t < 16; ++t) {
        float p = __expf(sreg[t] - M);
        lsum += p;
        const int jr = jb + t;
        #pragma unroll
        for (int d4 = 0; d4 < 16; ++d4) {
            float4 vv = *(const float4*)&Vs[jr][d4 * 4];
            av[d4].x += p * vv.x; av[d4].y += p * vv.y;
            av[d4].z += p * vv.z; av[d4].w += p * vv.w;
        }
    }

    // ---- intra-block merge of 4 waves (same (h,i), different j-quarters) ----
    pmL[w][l] = M; plL[w][l] = lsum;
    __syncthreads();
    float m0 = pmL[0][l], m1 = pmL[1][l], m2 = pmL[2][l], m3 = pmL[3][l];
    float Mg = fmaxf(fmaxf(m0, m1), fmaxf(m2, m3));
    float e = __expf(M - Mg);
    #pragma unroll
    for (int d4 = 0; d4 < 16; ++d4) {
        av[d4].x *= e; av[d4].y *= e; av[d4].z *= e; av[d4].w *= e;
    }
    float (*Sacc)[68] = Ks;   // reuse Ks (all reads done)
    if (w == 0) {
        #pragma unroll
        for (int d4 = 0; d4 < 16; ++d4) *(float4*)&Sacc[l][d4 * 4] = av[d4];
    }
    __syncthreads();
    if (w == 1) {
        #pragma unroll
        for (int d4 = 0; d4 < 16; ++d4) {
            float4 sv = *(const float4*)&Sacc[l][d4 * 4];
            sv.x += av[d4].x; sv.y += av[d4].y; sv.z += av[d4].z; sv.w += av[d4].w;
            *(float4*)&Sacc[l][d4 * 4] = sv;
        }
    }
    __syncthreads();
    if (w == 2) {
        #pragma unroll
        for (int d4 = 0; d4 < 16; ++d4) {
            float4 sv = *(const float4*)&Sacc[l][d4 * 4];
            sv.x += av[d4].x; sv.y += av[d4].y; sv.z += av[d4].z; sv.w += av[d4].w;
            *(float4*)&Sacc[l][d4 * 4] = sv;
        }
    }
    __syncthreads();
    if (w == 3) {
        float Lg = plL[0][l] * __expf(m0 - Mg) + plL[1][l] * __expf(m1 - Mg)
                 + plL[2][l] * __expf(m2 - Mg) + plL[3][l] * __expf(m3 - Mg);
        float* prow = pacc + ((size_t)((h * NQ + i) * 8 + c)) * 64;
        #pragma unroll
        for (int d4 = 0; d4 < 16; ++d4) {
            float4 sv = *(const float4*)&Sacc[l][d4 * 4];
            sv.x += av[d4].x; sv.y += av[d4].y; sv.z += av[d4].z; sv.w += av[d4].w;
            *(float4*)&prow[d4 * 4] = sv;
        }
        pm[(h * NQ + i) * 8 + c] = Mg;
        pl[(h * NQ + i) * 8 + c] = Lg;
    }
}

// --------------- cross-block merge of 8 partials -> inner -------------------
__global__ __launch_bounds__(256) void k_merge(float* __restrict__ ws)
{
    float* inner      = ws + IN_OFF;
    const float* pacc = ws + PA_OFF;
    const float* pm   = ws + PM_OFF;
    const float* pl   = ws + PL_OFF;

    const int g = blockIdx.x * 4 + (threadIdx.x >> 6);  // (h,i) row, 0..4095
    const int l = threadIdx.x & 63;                     // d

    float mv[8];
    #pragma unroll
    for (int cc = 0; cc < 8; ++cc) mv[cc] = pm[g * 8 + cc];
    float Mg = mv[0];
    #pragma unroll
    for (int cc = 1; cc < 8; ++cc) Mg = fmaxf(Mg, mv[cc]);
    float L = 0.f, a = 0.f;
    #pragma unroll
    for (int cc = 0; cc < 8; ++cc) {
        float e = __expf(mv[cc] - Mg);
        L += pl[g * 8 + cc] * e;
        a += pacc[(size_t)(g * 8 + cc) * 64 + l] * e;
    }
    const int h = g >> 9, i = g & 511;
    inner[i * DINNER + h * DHEAD + l] = a / L;
}

// ------------------------------------------------ K5: out = inner @ Wo + bo
__global__ __launch_bounds__(256) void k_out(
    const float* __restrict__ Wo, const float* __restrict__ bo,
    float* __restrict__ ws, float* __restrict__ outp)
{
    const float* inner = ws + IN_OFF;
    const int c0 = blockIdx.x * 32;
    const int i0 = blockIdx.y * 32;

    __shared__ alignas(16) float Xs[32][36];   // [kk][m]
    __shared__ alignas(16) float Bs[32][32];   // [kk][n]
    const int tx = threadIdx.x, ty = threadIdx.y;
    const int tid = ty * 16 + tx;

    float acc[2][2] = {};
    for (int k0 = 0; k0 < DINNER; k0 += 32) {
        {
            const int m = tid >> 3;
            const int kk0 = (tid & 7) * 4;
            float4 a4 = *(const float4*)&inner[(i0 + m) * DINNER + k0 + kk0];
            Xs[kk0 + 0][m] = a4.x; Xs[kk0 + 1][m] = a4.y;
            Xs[kk0 + 2][m] = a4.z; Xs[kk0 + 3][m] = a4.w;
        }
        {
            const int kk = tid >> 3;
            const int n0 = (tid & 7) * 4;
            *(float4*)&Bs[kk][n0] = *(const float4*)&Wo[(k0 + kk) * DMODEL + c0 + n0];
        }
        __syncthreads();
        #pragma unroll
        for (int kk = 0; kk < 32; ++kk) {
            float2 a2 = *(const float2*)&Xs[kk][ty * 2];
            float2 b2 = *(const float2*)&Bs[kk][tx * 2];
            acc[0][0] += a2.x * b2.x;
            acc[0][1] += a2.x * b2.y;
            acc[1][0] += a2.y * b2.x;
            acc[1][1] += a2.y * b2.y;
        }
        __syncthreads();
    }
    #pragma unroll
    for (int ia = 0; ia < 2; ++ia) {
        float2 o;
        o.x = acc[ia][0] + bo[c0 + tx * 2 + 0];
        o.y = acc[ia][1] + bo[c0 + tx * 2 + 1];
        *(float2*)&outp[(i0 + ty * 2 + ia) * DMODEL + c0 + tx * 2] = o;
    }
}

extern "C" void kernel_launch(void* const* d_in, const int* in_sizes, int n_in,
                              void* d_out, int out_size, void* d_ws, size_t ws_size,
                              hipStream_t stream)
{
    const float* x   = (const float*)d_in[0];
    const float* pos = (const float*)d_in[1];
    const float* Wq  = (const float*)d_in[2];
    const float* Wk  = (const float*)d_in[3];
    const float* Wv  = (const float*)d_in[4];
    const float* Wo  = (const float*)d_in[5];
    const float* bo  = (const float*)d_in[6];
    float* out = (float*)d_out;
    float* ws  = (float*)d_ws;

    k_proj<<<dim3(8, 8, 3), dim3(16, 16), 0, stream>>>(x, Wq, Wk, Wv, ws);
    k_qw<<<dim3(128), dim3(256), 0, stream>>>(Wk, ws);
    k_attn<<<dim3(8, 8, 8), dim3(256), 0, stream>>>(pos, ws);
    k_merge<<<dim3(1024), dim3(256), 0, stream>>>(ws);
    k_out<<<dim3(8, 16), dim3(16, 16), 0, stream>>>(Wo, bo, ws, out);
}